// Round 12
// baseline (675.350 us; speedup 1.0000x reference)
//
#include <hip/hip_runtime.h>
#include <stdint.h>

#define BB 16
#define TT 12
#define NN 4096
#define HH 64
#define EE 65536
#define MM (BB*TT)            // 192
#define ROWS (MM*NN)          // 786432
#define TOT (ROWS*HH)         // 50331648
#define NBUCKET 256
#define T2_GRID 2048
#define T2_NT 6               // tiles per block = 12288 / 2048

typedef __attribute__((ext_vector_type(8))) __bf16 bf16x8;
typedef __attribute__((ext_vector_type(8))) unsigned short us8;
typedef __attribute__((ext_vector_type(4))) float f32x4;
typedef __attribute__((ext_vector_type(2))) unsigned int ui2;

__device__ __forceinline__ unsigned short f2bf(float f){
  unsigned u = __builtin_bit_cast(unsigned, f);
  u += 0x7fffu + ((u >> 16) & 1u);
  return (unsigned short)(u >> 16);
}
__device__ __forceinline__ float bf2f(unsigned short s){
  unsigned u = ((unsigned)s) << 16;
  return __builtin_bit_cast(float, u);
}
__device__ __forceinline__ float lo2f(unsigned v){ return __builtin_bit_cast(float, v << 16); }
__device__ __forceinline__ float hi2f(unsigned v){ return __builtin_bit_cast(float, v & 0xffff0000u); }
__device__ __forceinline__ bf16x8 ldbf8(const unsigned short* p){
  us8 u = *reinterpret_cast<const us8*>(p);
  return __builtin_bit_cast(bf16x8, u);
}

// ---------------- graph preprocessing ----------------

__global__ void k_deg_cnt(const int* __restrict__ src, const int* __restrict__ dst,
                          const float* __restrict__ attr,
                          float* __restrict__ deg, int* __restrict__ cnt){
  int e = blockIdx.x * 256 + threadIdx.x;
  if (e < EE){
    atomicAdd(&deg[src[e]], attr[e]);
    atomicAdd(&cnt[dst[e]], 1);
  }
}

__global__ void k_wn(const int* __restrict__ src, const int* __restrict__ dst,
                     const float* __restrict__ attr, const float* __restrict__ deg,
                     float* __restrict__ wn){
  int e = blockIdx.x * 256 + threadIdx.x;
  if (e < EE){
    float ds = deg[src[e]], dd = deg[dst[e]];
    float rs = ds > 0.f ? rsqrtf(ds) : 0.f;
    float rd = dd > 0.f ? rsqrtf(dd) : 0.f;
    wn[e] = -rs * attr[e] * rd;
  }
}

__global__ void k_scan(const int* __restrict__ cnt, int* __restrict__ rowptr,
                       int* __restrict__ fill){
  __shared__ int lds[1024];
  int t = threadIdx.x;
  int c0 = cnt[4*t], c1 = cnt[4*t+1], c2 = cnt[4*t+2], c3 = cnt[4*t+3];
  int s = c0 + c1 + c2 + c3;
  lds[t] = s; __syncthreads();
  for (int off = 1; off < 1024; off <<= 1){
    int v = (t >= off) ? lds[t-off] : 0;
    __syncthreads();
    lds[t] += v;
    __syncthreads();
  }
  int excl = lds[t] - s;
  rowptr[4*t]   = excl;            fill[4*t]   = excl;
  rowptr[4*t+1] = excl + c0;       fill[4*t+1] = excl + c0;
  rowptr[4*t+2] = excl + c0 + c1;  fill[4*t+2] = excl + c0 + c1;
  rowptr[4*t+3] = excl + c0+c1+c2; fill[4*t+3] = excl + c0+c1+c2;
  if (t == 1023) rowptr[4096] = lds[1023];
}

__global__ void k_csr(const int* __restrict__ dst, const int* __restrict__ src,
                      const float* __restrict__ wn, int* __restrict__ fill,
                      ui2* __restrict__ csre){
  int e = blockIdx.x * 256 + threadIdx.x;
  if (e < EE){
    int d = dst[e];
    int pos = atomicAdd(&fill[d], 1);
    ui2 mw;
    mw.x = (unsigned)src[e];
    mw.y = __builtin_bit_cast(unsigned, wn[e]);
    csre[pos] = mw;
  }
}

// ---------------- weight prep (bf16 MFMA fragment layout) ----------------

__global__ void k_wprep(const float* __restrict__ chebW,
                        const float* __restrict__ w1, const float* __restrict__ w2,
                        const float* __restrict__ w3,
                        const float* __restrict__ e1w, const float* __restrict__ e1b,
                        const float* __restrict__ e2w, const float* __restrict__ e2b,
                        const float* __restrict__ e3w, const float* __restrict__ e3b,
                        unsigned short* __restrict__ wfD, unsigned short* __restrict__ wfF,
                        unsigned short* __restrict__ wfE){
  int gt = blockIdx.x * blockDim.x + threadIdx.x;
  int stride = gridDim.x * blockDim.x;
  for (int i = gt; i < 12288; i += stride){
    int kl = i & 31, cc = (i >> 5) & 63, mk = i >> 11;
    int kt = mk & 1, mat = mk >> 1;
    int k = kt * 32 + kl;
    float v;
    if (mat == 0)      v = chebW[k*64 + cc] - chebW[2*4096 + k*64 + cc];
    else if (mat == 1) v = chebW[4096 + k*64 + cc];
    else               v = 2.f * chebW[2*4096 + k*64 + cc];
    wfD[i] = f2bf(v);
  }
  for (int i = gt; i < 36864; i += stride){
    int kl = i & 31, hh = (i >> 5) & 63, ck = i >> 11;
    int kt = ck % 6, conv = ck / 6;
    int k = kt * 32 + kl, dt = k >> 6, ci = k & 63;
    const float* w = (conv == 0) ? w1 : ((conv == 1) ? w2 : w3);
    wfF[i] = f2bf(w[(hh*64 + ci)*3 + dt]);
  }
  for (int i = gt; i < 6144; i += stride){
    int k = i & 31, hh = (i >> 5) & 63, conv = i >> 11;
    const float* w = (conv == 0) ? e1w : ((conv == 1) ? e2w : e3w);
    const float* b = (conv == 0) ? e1b : ((conv == 1) ? e2b : e3b);
    float v = 0.f;
    if (k < 6)       v = w[(hh*2 + (k & 1))*3 + (k >> 1)];
    else if (k == 6) v = b[hh];
    wfE[i] = f2bf(v);
  }
}

// ---------------- temporal conv 1 (Cin=2) via MFMA; output [n][m][c] ----------------

__global__ __launch_bounds__(256) void k_temporal1(
    const float* __restrict__ x, const unsigned short* __restrict__ wfE,
    unsigned short* __restrict__ U){
  const int tid = threadIdx.x;
  const int wv = tid >> 6, lane = tid & 63;
  const int lhi = lane >> 4, llo = lane & 15;
  const int blk = blockIdx.x;
  const int bt = blk >> 6, nb = blk & 63;
  const int t = bt - (bt / TT) * TT;

  us8 au = {0,0,0,0,0,0,0,0};
  if (lhi == 0){
    const int n = nb*64 + wv*16 + llo;
    #pragma unroll
    for (int dt = 0; dt < 3; ++dt){
      int tp = t + dt - 1;
      if (tp >= 0 && tp < TT){
        const float2 v = *reinterpret_cast<const float2*>(
            x + ((size_t)(bt + dt - 1) * NN + n) * 2);
        if (dt == 0){ au[0] = f2bf(v.x); au[1] = f2bf(v.y); }
        if (dt == 1){ au[2] = f2bf(v.x); au[3] = f2bf(v.y); }
        if (dt == 2){ au[4] = f2bf(v.x); au[5] = f2bf(v.y); }
      }
    }
    au[6] = 0x3f80;  // 1.0 -> bias column
  }
  const bf16x8 af = __builtin_bit_cast(bf16x8, au);

  const f32x4 z = {0.f, 0.f, 0.f, 0.f};
  f32x4 acc[3][4];
  #pragma unroll
  for (int conv = 0; conv < 3; ++conv)
    #pragma unroll
    for (int ht = 0; ht < 4; ++ht){
      bf16x8 bw = ldbf8(wfE + (size_t)((conv*64) + ht*16 + llo)*32 + lhi*8);
      acc[conv][ht] = __builtin_amdgcn_mfma_f32_16x16x32_bf16(af, bw, z, 0, 0, 0);
    }

  #pragma unroll
  for (int ht = 0; ht < 4; ++ht){
    const int h = ht*16 + llo;
    #pragma unroll
    for (int i = 0; i < 4; ++i){
      float p = acc[0][ht][i];
      float q = acc[1][ht][i];
      float r = acc[2][ht][i];
      float sig = 1.f / (1.f + __expf(-q));
      float o = fmaxf(fmaf(p, sig, r), 0.f);
      const int n = nb*64 + wv*16 + lhi*4 + i;
      U[((size_t)n * MM + bt) * 64 + h] = f2bf(o);   // [n][m][c]
    }
  }
}

// ---------------- FUSED spmv1 + cheb GEMM, v3: wave-private, barrier-free ----------------
// block <-> (mg, ng) as v2, but each wave owns the 16 rows (4 nodes x 4 m) it
// gathers: LDS is 4 private 2KB quadrants, NO __syncthreads (intra-wave LDS RAW
// is compiler-handled via lgkmcnt). Waves drift independently -> one wave's
// MFMA/epilogue overlaps other waves' gathers, no convoy. Plain loads
// (sc0 null - R11; nt catastrophic - R8).

__global__ __launch_bounds__(256) void k_fused_sc(
    const unsigned short* __restrict__ U,
    const int* __restrict__ rowptr, const ui2* __restrict__ csre,
    const unsigned short* __restrict__ wfD, const float* __restrict__ cheb_b,
    unsigned short* __restrict__ G0bf, unsigned short* __restrict__ P){
  __shared__ unsigned short vlds[4096];   // 4 x (16 rows x 64 ch), XOR-swizzled
  const int tid = threadIdx.x;
  int blk = blockIdx.x;
  blk = (blk & 7) * 1536 + (blk >> 3);    // XCD chunk swizzle (12288/8 = 1536)
  const int mg = blk >> 8;                // [0,48): 4 m-planes
  const int ng = blk & 255;               // [0,256): 16 nodes
  const int wv = tid >> 6, lane = tid & 63;
  const int p = lane >> 4, c4 = lane & 15;           // plane, 4-ch block
  const int loff = p*64 + c4*4;                      // elem offset in 512B slab

  const unsigned short* Umg = U + (size_t)mg * 256;  // + src*12288 + loff
  char* wq = reinterpret_cast<char*>(vlds) + wv*2048;  // wave-private quadrant

  // ---- Phase A: gather this wave's 4 nodes ----
  for (int j = 0; j < 4; ++j){
    const int n = ng*16 + wv*4 + j;
    const int e0 = __builtin_amdgcn_readfirstlane(rowptr[n]);
    const int e1 = __builtin_amdgcn_readfirstlane(rowptr[n+1]);
    float a0 = 0.f, a1 = 0.f, a2 = 0.f, a3 = 0.f;
    for (int e = e0; e < e1; e += 8){
      int ss[8]; float ww[8];
      #pragma unroll
      for (int u = 0; u < 8; ++u){
        const int ee = e + u;
        const bool in = ee < e1;
        const ui2 mw = csre[in ? ee : e0];
        ss[u] = (int)__builtin_amdgcn_readfirstlane(mw.x);
        const float wvv = __builtin_bit_cast(float, __builtin_amdgcn_readfirstlane(mw.y));
        ww[u] = in ? wvv : 0.f;
      }
      ui2 d[8];
      #pragma unroll
      for (int u = 0; u < 8; ++u)
        d[u] = *reinterpret_cast<const ui2*>(Umg + (size_t)ss[u] * 12288 + loff);
      #pragma unroll
      for (int u = 0; u < 8; ++u){
        const float w = ww[u];
        a0 = fmaf(w, lo2f(d[u].x), a0);
        a1 = fmaf(w, hi2f(d[u].x), a1);
        a2 = fmaf(w, lo2f(d[u].y), a2);
        a3 = fmaf(w, hi2f(d[u].y), a3);
      }
    }
    const int r = j*4 + p;               // row_local within wave quadrant
    const int byteoff = r*128 + ((c4*8) ^ ((r & 7) << 4));
    ushort4 pk;
    pk.x = f2bf(a0); pk.y = f2bf(a1); pk.z = f2bf(a2); pk.w = f2bf(a3);
    *reinterpret_cast<ushort4*>(wq + byteoff) = pk;
  }
  // NO __syncthreads: quadrant is wave-private, compiler inserts lgkmcnt waits.

  // ---- Phase B: this wave's 16 rows x 64 out-channels ----
  const int lhi = lane >> 4, llo = lane & 15;
  // A-frags (row = llo): U from global, V from the wave quadrant
  const size_t grA = ((size_t)(ng*16 + wv*4 + (llo >> 2))) * MM + mg*4 + (llo & 3);
  const unsigned short* up = U + grA*64 + lhi*8;
  bf16x8 au[2], av[2];
  #pragma unroll
  for (int kt = 0; kt < 2; ++kt){
    au[kt] = ldbf8(up + kt*32);
    const int vboff = llo*128 + (((kt*64) + lhi*16) ^ ((llo & 7) << 4));
    av[kt] = __builtin_bit_cast(bf16x8, *reinterpret_cast<const us8*>(wq + vboff));
  }
  const f32x4 z = {0.f, 0.f, 0.f, 0.f};
  #pragma unroll
  for (int ct = 0; ct < 4; ++ct){
    const int c = ct*16 + llo;           // out channel (B/D col = llo)
    f32x4 accG = z, accP = z;
    #pragma unroll
    for (int kt = 0; kt < 2; ++kt){
      bf16x8 bA  = ldbf8(wfD + (size_t)((0*2 + kt)*64 + c)*32 + lhi*8);
      bf16x8 bW1 = ldbf8(wfD + (size_t)((1*2 + kt)*64 + c)*32 + lhi*8);
      bf16x8 bW2 = ldbf8(wfD + (size_t)((2*2 + kt)*64 + c)*32 + lhi*8);
      accG = __builtin_amdgcn_mfma_f32_16x16x32_bf16(au[kt], bA,  accG, 0, 0, 0);
      accG = __builtin_amdgcn_mfma_f32_16x16x32_bf16(av[kt], bW1, accG, 0, 0, 0);
      accP = __builtin_amdgcn_mfma_f32_16x16x32_bf16(av[kt], bW2, accP, 0, 0, 0);
    }
    const float bias = cheb_b[c];
    #pragma unroll
    for (int i = 0; i < 4; ++i){
      const int rl = lhi*4 + i;          // D row = row_local
      const size_t gr = ((size_t)(ng*16 + wv*4 + (rl >> 2))) * MM + mg*4 + (rl & 3);
      G0bf[gr*64 + c] = f2bf(accG[i] + bias);
      P[gr*64 + c]    = f2bf(accP[i]);
    }
  }
}

// ---------------- spmv2 on [n][m][c]: g = relu(G0 + S·P), plain gathers ----------------

__global__ __launch_bounds__(256) void k_spmv2(
    const unsigned short* __restrict__ X,
    const int* __restrict__ rowptr,
    const ui2* __restrict__ csre,
    const unsigned short* __restrict__ G0bf,
    unsigned short* __restrict__ Y){
  constexpr int EU = 16;
  const int nb = gridDim.x;
  int bs = (blockIdx.x & 7) * (nb >> 3) + (blockIdx.x >> 3);
  int wg = bs * 4 + (threadIdx.x >> 6);
  wg = __builtin_amdgcn_readfirstlane(wg);
  const int lane = threadIdx.x & 63;
  const int mg = wg >> 12, n = wg & (NN-1);
  const int e0 = __builtin_amdgcn_readfirstlane(rowptr[n]);
  const int e1 = __builtin_amdgcn_readfirstlane(rowptr[n+1]);
  const unsigned short* Xmg = X + (size_t)mg * 256;
  const int loff = lane * 4;

  float a0 = 0.f, a1 = 0.f, a2 = 0.f, a3 = 0.f;

  for (int e = e0; e < e1; e += EU){
    int ss[EU]; float ww[EU];
    #pragma unroll
    for (int u = 0; u < EU; ++u){
      const int ee = e + u;
      const bool in = ee < e1;
      const ui2 mw = csre[in ? ee : e0];
      ss[u] = (int)__builtin_amdgcn_readfirstlane(mw.x);
      const float wv = __builtin_bit_cast(float, __builtin_amdgcn_readfirstlane(mw.y));
      ww[u] = in ? wv : 0.f;
    }
    ui2 d[EU];
    #pragma unroll
    for (int u = 0; u < EU; ++u)
      d[u] = *reinterpret_cast<const ui2*>(Xmg + (size_t)ss[u] * 12288 + loff);
    #pragma unroll
    for (int u = 0; u < EU; ++u){
      const float w = ww[u];
      a0 = fmaf(w, lo2f(d[u].x), a0);
      a1 = fmaf(w, hi2f(d[u].x), a1);
      a2 = fmaf(w, lo2f(d[u].y), a2);
      a3 = fmaf(w, hi2f(d[u].y), a3);
    }
  }

  const size_t oidx = (size_t)n * 12288 + mg * 256 + loff;
  {
    ui2 gd = *reinterpret_cast<const ui2*>(G0bf + oidx);
    a0 = fmaxf(a0 + lo2f(gd.x), 0.f);
    a1 = fmaxf(a1 + hi2f(gd.x), 0.f);
    a2 = fmaxf(a2 + lo2f(gd.y), 0.f);
    a3 = fmaxf(a3 + hi2f(gd.y), 0.f);
  }
  ui2 o;
  o.x = (unsigned)f2bf(a0) | ((unsigned)f2bf(a1) << 16);
  o.y = (unsigned)f2bf(a2) | ((unsigned)f2bf(a3) << 16);
  *reinterpret_cast<ui2*>(Y + oidx) = o;
}

// ---------------- temporal conv 2: persistent blocks, reg weights, LDS-staged g ----------------

__device__ __forceinline__ void t2_load(const unsigned short* __restrict__ g,
                                        int tile, int tid, uint4* st){
  const int bt = tile >> 6, nb = tile & 63;
  const int t = bt - (bt / TT) * TT;
  #pragma unroll
  for (int j = 0; j < 6; ++j){
    const int plane = j >> 1;
    const int tp = t + plane - 1;
    const int idx = ((j & 1) << 8) + tid;      // 0..511 within plane
    const int row = idx >> 3;                  // 0..63
    const int innerb = (idx & 7) * 16;         // byte offset within 128B row
    if (tp >= 0 && tp < TT){
      const unsigned short* sp = g
          + ((size_t)(nb*64 + row) * MM + (bt + plane - 1)) * 64
          + ((innerb ^ ((row & 7) << 4)) >> 1);
      st[j] = *reinterpret_cast<const uint4*>(sp);
    } else {
      st[j] = make_uint4(0u, 0u, 0u, 0u);
    }
  }
}

__global__ __launch_bounds__(256, 2) void k_temporal2(
    const unsigned short* __restrict__ g,
    const unsigned short* __restrict__ wfF,
    const float* __restrict__ b1, const float* __restrict__ b2, const float* __restrict__ b3,
    unsigned short* __restrict__ obf, float* __restrict__ bnstat2){
  __shared__ unsigned short smem[2][12288];    // 2 x 24KB
  const int tid = threadIdx.x;
  const int wv = tid >> 6, lane = tid & 63;
  const int lhi = lane >> 4, llo = lane & 15;
  const int h = wv * 16 + llo;                 // A-fragment row
  const int h0 = wv * 16 + lhi * 4;            // D rows: 4 consecutive h per thread

  bf16x8 bw[3][6];
  #pragma unroll
  for (int cv = 0; cv < 3; ++cv)
    #pragma unroll
    for (int kt = 0; kt < 6; ++kt)
      bw[cv][kt] = ldbf8(wfF + (size_t)((cv*6 + kt)*64 + h)*32 + lhi*8);

  const f32x4 vb1 = *reinterpret_cast<const f32x4*>(b1 + h0);
  const f32x4 vb2 = *reinterpret_cast<const f32x4*>(b2 + h0);
  const f32x4 vb3 = *reinterpret_cast<const f32x4*>(b3 + h0);
  const f32x4 z = {0.f, 0.f, 0.f, 0.f};

  uint4 st[6];
  t2_load(g, blockIdx.x, tid, st);
  #pragma unroll
  for (int j = 0; j < 6; ++j)
    *reinterpret_cast<uint4*>(&smem[0][(size_t)(j*256 + tid) * 8]) = st[j];
  __syncthreads();

  int cur = 0;
  for (int it = 0; it < T2_NT; ++it){
    const int tile = blockIdx.x + it * T2_GRID;
    const int bt = tile >> 6, nb = tile & 63;

    if (it + 1 < T2_NT)
      t2_load(g, tile + T2_GRID, tid, st);     // issue early; consumed after compute

    const unsigned short* sb = smem[cur];
    f32x4 acc[3][4];
    #pragma unroll
    for (int cv = 0; cv < 3; ++cv)
      #pragma unroll
      for (int rt = 0; rt < 4; ++rt) acc[cv][rt] = z;

    #pragma unroll
    for (int kt = 0; kt < 6; ++kt){
      const int dt = kt >> 1;
      const int qb = (kt & 1) * 64 + lhi * 16; // byte offset within row
      #pragma unroll
      for (int rt = 0; rt < 4; ++rt){
        const int row = rt*16 + llo;
        bf16x8 a = __builtin_bit_cast(bf16x8, *reinterpret_cast<const us8*>(
            sb + dt*4096 + row*64 + ((qb ^ ((row & 7) << 4)) >> 1)));
        acc[0][rt] = __builtin_amdgcn_mfma_f32_16x16x32_bf16(bw[0][kt], a, acc[0][rt], 0, 0, 0);
        acc[1][rt] = __builtin_amdgcn_mfma_f32_16x16x32_bf16(bw[1][kt], a, acc[1][rt], 0, 0, 0);
        acc[2][rt] = __builtin_amdgcn_mfma_f32_16x16x32_bf16(bw[2][kt], a, acc[2][rt], 0, 0, 0);
      }
    }

    f32x4 lsum = z, lsq = z;
    #pragma unroll
    for (int rt = 0; rt < 4; ++rt){
      const int n = nb*64 + rt*16 + llo;       // D col
      ushort4 pk;
      unsigned short* pp = reinterpret_cast<unsigned short*>(&pk);
      #pragma unroll
      for (int i = 0; i < 4; ++i){
        float p = acc[0][rt][i] + vb1[i];
        float q = acc[1][rt][i] + vb2[i];
        float r = acc[2][rt][i] + vb3[i];
        float sig = 1.f / (1.f + __expf(-q));
        float o = fmaxf(fmaf(p, sig, r), 0.f);
        pp[i] = f2bf(o);
        lsum[i] += o; lsq[i] = fmaf(o, o, lsq[i]);
      }
      *reinterpret_cast<ushort4*>(&obf[((size_t)bt * NN + n) * 64 + h0]) = pk;
    }
    #pragma unroll
    for (int m = 1; m < 16; m <<= 1){
      #pragma unroll
      for (int i = 0; i < 4; ++i){
        lsum[i] += __shfl_xor(lsum[i], m);
        lsq[i]  += __shfl_xor(lsq[i], m);
      }
    }
    if (llo == 0){
      float* bs = bnstat2 + (size_t)(tile & (NBUCKET-1)) * 128;
      #pragma unroll
      for (int i = 0; i < 4; ++i){
        atomicAdd(&bs[h0 + i], lsum[i]);
        atomicAdd(&bs[64 + h0 + i], lsq[i]);
      }
    }

    if (it + 1 < T2_NT){
      #pragma unroll
      for (int j = 0; j < 6; ++j)
        *reinterpret_cast<uint4*>(&smem[cur ^ 1][(size_t)(j*256 + tid) * 8]) = st[j];
      __syncthreads();
      cur ^= 1;
    }
  }
}

// ---------------- BN bucket reduce + apply ----------------

__global__ void k_bnfinal(const float* __restrict__ bnstat2, float* __restrict__ bnstat){
  int t = threadIdx.x;   // 0..127
  float s = 0.f;
  for (int b = 0; b < NBUCKET; ++b) s += bnstat2[(size_t)b * 128 + t];
  bnstat[t] = s;
}

__global__ __launch_bounds__(256) void k_bnapply(
    const unsigned short* __restrict__ obf, float* __restrict__ out,
    const float* __restrict__ bnstat,
    const float* __restrict__ gamma, const float* __restrict__ beta){
  __shared__ float ssc[64], sfb[64];
  int tid = threadIdx.x;
  if (tid < 64){
    const float inv = 1.f / (float)ROWS;
    float s = bnstat[tid], q = bnstat[64 + tid];
    float mu = s * inv;
    float var = q * inv - mu * mu;
    if (var < 0.f) var = 0.f;
    float sc = gamma[tid] * rsqrtf(var + 1e-5f);
    ssc[tid] = sc;
    sfb[tid] = beta[tid] - mu * sc;   // out = f*sc + sfb
  }
  __syncthreads();
  const int ngrp = TOT / 8;
  for (int i = blockIdx.x * 256 + tid; i < ngrp; i += gridDim.x * 256){
    us8 v = *reinterpret_cast<const us8*>(obf + (size_t)i * 8);
    const int c0 = (i * 8) & 63;
    f32x4 lo, hi;
    #pragma unroll
    for (int j = 0; j < 4; ++j)
      lo[j] = fmaf(bf2f(v[j]), ssc[c0 + j], sfb[c0 + j]);
    #pragma unroll
    for (int j = 0; j < 4; ++j)
      hi[j] = fmaf(bf2f(v[4 + j]), ssc[c0 + 4 + j], sfb[c0 + 4 + j]);
    *reinterpret_cast<f32x4*>(out + (size_t)i * 8)     = lo;
    *reinterpret_cast<f32x4*>(out + (size_t)i * 8 + 4) = hi;
  }
}

// ---------------- launch ----------------

extern "C" void kernel_launch(void* const* d_in, const int* in_sizes, int n_in,
                              void* d_out, int out_size, void* d_ws, size_t ws_size,
                              hipStream_t stream){
  const float* x     = (const float*)d_in[0];
  const int*   ei    = (const int*)d_in[1];
  const float* attr  = (const float*)d_in[2];
  const float* t1w1  = (const float*)d_in[3];
  const float* t1b1  = (const float*)d_in[4];
  const float* t1w2  = (const float*)d_in[5];
  const float* t1b2  = (const float*)d_in[6];
  const float* t1w3  = (const float*)d_in[7];
  const float* t1b3  = (const float*)d_in[8];
  const float* chebW = (const float*)d_in[9];
  const float* chebB = (const float*)d_in[10];
  const float* t2w1  = (const float*)d_in[11];
  const float* t2b1  = (const float*)d_in[12];
  const float* t2w2  = (const float*)d_in[13];
  const float* t2b2  = (const float*)d_in[14];
  const float* t2w3  = (const float*)d_in[15];
  const float* t2b3  = (const float*)d_in[16];
  const float* bng   = (const float*)d_in[17];
  const float* bnb   = (const float*)d_in[18];
  const int* src = ei;
  const int* dst = ei + EE;

  const size_t SZ_U = (size_t)ROWS * 64 * 2;
  char* ws = (char*)d_ws;
  unsigned short* bufA = (unsigned short*)ws;
  unsigned short* bufB = (unsigned short*)(ws + SZ_U);
  size_t off = 2 * SZ_U;
  float* deg    = (float*)(ws + off); off += 4096 * 4;
  int*   cnt    = (int*)(ws + off);   off += 4096 * 4;
  int*   rowptr = (int*)(ws + off);   off += 4128 * 4;
  int*   fill   = (int*)(ws + off);   off += 4096 * 4;
  float* wn     = (float*)(ws + off); off += EE * 4;
  ui2*   csre   = (ui2*)(ws + off);   off += EE * 8;
  unsigned short* wfD = (unsigned short*)(ws + off); off += 12288 * 2;
  unsigned short* wfF = (unsigned short*)(ws + off); off += 36864 * 2;
  unsigned short* wfE = (unsigned short*)(ws + off); off += 6144 * 2;
  float* bnstat = (float*)(ws + off); off += 128 * 4;
  float* bnstat2 = (float*)(ws + off); off += NBUCKET * 128 * 4;

  unsigned short* G0bf = (unsigned short*)d_out;  // bf16 cheb pre-relu ([n][m][c] rows)

  hipMemsetAsync(deg, 0, 4096 * 4, stream);
  hipMemsetAsync(cnt, 0, 4096 * 4, stream);
  hipMemsetAsync(bnstat2, 0, NBUCKET * 128 * 4, stream);

  k_deg_cnt<<<EE/256, 256, 0, stream>>>(src, dst, attr, deg, cnt);
  k_wn<<<EE/256, 256, 0, stream>>>(src, dst, attr, deg, wn);
  k_scan<<<1, 1024, 0, stream>>>(cnt, rowptr, fill);
  k_csr<<<EE/256, 256, 0, stream>>>(dst, src, wn, fill, csre);
  k_wprep<<<64, 256, 0, stream>>>(chebW, t2w1, t2w2, t2w3,
                                  t1w1, t1b1, t1w2, t1b2, t1w3, t1b3,
                                  wfD, wfF, wfE);

  k_temporal1<<<ROWS/64, 256, 0, stream>>>(x, wfE, bufA /* U */);
  k_fused_sc<<<ROWS/64, 256, 0, stream>>>(bufA /* U */, rowptr, csre, wfD, chebB,
                                          G0bf, bufB /* P */);
  k_spmv2<<<(MM/4)*NN/4, 256, 0, stream>>>(bufB /* P */, rowptr, csre, G0bf, bufA /* g */);
  k_temporal2<<<T2_GRID, 256, 0, stream>>>(bufA /* g */, wfF, t2b1, t2b2, t2b3,
                                           bufB /* obf */, bnstat2);
  k_bnfinal<<<1, 128, 0, stream>>>(bnstat2, bnstat);
  k_bnapply<<<2048, 256, 0, stream>>>(bufB /* obf */, (float*)d_out, bnstat, bng, bnb);
}

// Round 13
// 640.018 us; speedup vs baseline: 1.0552x; 1.0552x over previous
//
#include <hip/hip_runtime.h>
#include <stdint.h>

#define BB 16
#define TT 12
#define NN 4096
#define HH 64
#define EE 65536
#define MM (BB*TT)            // 192
#define ROWS (MM*NN)          // 786432
#define TOT (ROWS*HH)         // 50331648
#define NBUCKET 256
#define T2_GRID 2048
#define T2_NT 6               // tiles per block = 12288 / 2048

typedef __attribute__((ext_vector_type(8))) __bf16 bf16x8;
typedef __attribute__((ext_vector_type(8))) unsigned short us8;
typedef __attribute__((ext_vector_type(4))) float f32x4;
typedef __attribute__((ext_vector_type(2))) unsigned int ui2;

__device__ __forceinline__ unsigned short f2bf(float f){
  unsigned u = __builtin_bit_cast(unsigned, f);
  u += 0x7fffu + ((u >> 16) & 1u);
  return (unsigned short)(u >> 16);
}
__device__ __forceinline__ float bf2f(unsigned short s){
  unsigned u = ((unsigned)s) << 16;
  return __builtin_bit_cast(float, u);
}
__device__ __forceinline__ float lo2f(unsigned v){ return __builtin_bit_cast(float, v << 16); }
__device__ __forceinline__ float hi2f(unsigned v){ return __builtin_bit_cast(float, v & 0xffff0000u); }
__device__ __forceinline__ bf16x8 ldbf8(const unsigned short* p){
  us8 u = *reinterpret_cast<const us8*>(p);
  return __builtin_bit_cast(bf16x8, u);
}

// ---------------- graph preprocessing ----------------

__global__ void k_deg_cnt(const int* __restrict__ src, const int* __restrict__ dst,
                          const float* __restrict__ attr,
                          float* __restrict__ deg, int* __restrict__ cnt){
  int e = blockIdx.x * 256 + threadIdx.x;
  if (e < EE){
    atomicAdd(&deg[src[e]], attr[e]);
    atomicAdd(&cnt[dst[e]], 1);
  }
}

__global__ void k_wn(const int* __restrict__ src, const int* __restrict__ dst,
                     const float* __restrict__ attr, const float* __restrict__ deg,
                     float* __restrict__ wn){
  int e = blockIdx.x * 256 + threadIdx.x;
  if (e < EE){
    float ds = deg[src[e]], dd = deg[dst[e]];
    float rs = ds > 0.f ? rsqrtf(ds) : 0.f;
    float rd = dd > 0.f ? rsqrtf(dd) : 0.f;
    wn[e] = -rs * attr[e] * rd;
  }
}

__global__ void k_scan(const int* __restrict__ cnt, int* __restrict__ rowptr,
                       int* __restrict__ fill){
  __shared__ int lds[1024];
  int t = threadIdx.x;
  int c0 = cnt[4*t], c1 = cnt[4*t+1], c2 = cnt[4*t+2], c3 = cnt[4*t+3];
  int s = c0 + c1 + c2 + c3;
  lds[t] = s; __syncthreads();
  for (int off = 1; off < 1024; off <<= 1){
    int v = (t >= off) ? lds[t-off] : 0;
    __syncthreads();
    lds[t] += v;
    __syncthreads();
  }
  int excl = lds[t] - s;
  rowptr[4*t]   = excl;            fill[4*t]   = excl;
  rowptr[4*t+1] = excl + c0;       fill[4*t+1] = excl + c0;
  rowptr[4*t+2] = excl + c0 + c1;  fill[4*t+2] = excl + c0 + c1;
  rowptr[4*t+3] = excl + c0+c1+c2; fill[4*t+3] = excl + c0+c1+c2;
  if (t == 1023) rowptr[4096] = lds[1023];
}

__global__ void k_csr(const int* __restrict__ dst, const int* __restrict__ src,
                      const float* __restrict__ wn, int* __restrict__ fill,
                      ui2* __restrict__ csre){
  int e = blockIdx.x * 256 + threadIdx.x;
  if (e < EE){
    int d = dst[e];
    int pos = atomicAdd(&fill[d], 1);
    ui2 mw;
    mw.x = (unsigned)src[e];
    mw.y = __builtin_bit_cast(unsigned, wn[e]);
    csre[pos] = mw;
  }
}

// ---------------- weight prep (bf16 MFMA fragment layout) ----------------

__global__ void k_wprep(const float* __restrict__ chebW,
                        const float* __restrict__ w1, const float* __restrict__ w2,
                        const float* __restrict__ w3,
                        const float* __restrict__ e1w, const float* __restrict__ e1b,
                        const float* __restrict__ e2w, const float* __restrict__ e2b,
                        const float* __restrict__ e3w, const float* __restrict__ e3b,
                        unsigned short* __restrict__ wfD, unsigned short* __restrict__ wfF,
                        unsigned short* __restrict__ wfE){
  int gt = blockIdx.x * blockDim.x + threadIdx.x;
  int stride = gridDim.x * blockDim.x;
  for (int i = gt; i < 12288; i += stride){
    int kl = i & 31, cc = (i >> 5) & 63, mk = i >> 11;
    int kt = mk & 1, mat = mk >> 1;
    int k = kt * 32 + kl;
    float v;
    if (mat == 0)      v = chebW[k*64 + cc] - chebW[2*4096 + k*64 + cc];
    else if (mat == 1) v = chebW[4096 + k*64 + cc];
    else               v = 2.f * chebW[2*4096 + k*64 + cc];
    wfD[i] = f2bf(v);
  }
  for (int i = gt; i < 36864; i += stride){
    int kl = i & 31, hh = (i >> 5) & 63, ck = i >> 11;
    int kt = ck % 6, conv = ck / 6;
    int k = kt * 32 + kl, dt = k >> 6, ci = k & 63;
    const float* w = (conv == 0) ? w1 : ((conv == 1) ? w2 : w3);
    wfF[i] = f2bf(w[(hh*64 + ci)*3 + dt]);
  }
  for (int i = gt; i < 6144; i += stride){
    int k = i & 31, hh = (i >> 5) & 63, conv = i >> 11;
    const float* w = (conv == 0) ? e1w : ((conv == 1) ? e2w : e3w);
    const float* b = (conv == 0) ? e1b : ((conv == 1) ? e2b : e3b);
    float v = 0.f;
    if (k < 6)       v = w[(hh*2 + (k & 1))*3 + (k >> 1)];
    else if (k == 6) v = b[hh];
    wfE[i] = f2bf(v);
  }
}

// ---------------- temporal conv 1 (Cin=2) via MFMA; output [n][m][c] ----------------

__global__ __launch_bounds__(256) void k_temporal1(
    const float* __restrict__ x, const unsigned short* __restrict__ wfE,
    unsigned short* __restrict__ U){
  const int tid = threadIdx.x;
  const int wv = tid >> 6, lane = tid & 63;
  const int lhi = lane >> 4, llo = lane & 15;
  const int blk = blockIdx.x;
  const int bt = blk >> 6, nb = blk & 63;
  const int t = bt - (bt / TT) * TT;

  us8 au = {0,0,0,0,0,0,0,0};
  if (lhi == 0){
    const int n = nb*64 + wv*16 + llo;
    #pragma unroll
    for (int dt = 0; dt < 3; ++dt){
      int tp = t + dt - 1;
      if (tp >= 0 && tp < TT){
        const float2 v = *reinterpret_cast<const float2*>(
            x + ((size_t)(bt + dt - 1) * NN + n) * 2);
        if (dt == 0){ au[0] = f2bf(v.x); au[1] = f2bf(v.y); }
        if (dt == 1){ au[2] = f2bf(v.x); au[3] = f2bf(v.y); }
        if (dt == 2){ au[4] = f2bf(v.x); au[5] = f2bf(v.y); }
      }
    }
    au[6] = 0x3f80;  // 1.0 -> bias column
  }
  const bf16x8 af = __builtin_bit_cast(bf16x8, au);

  const f32x4 z = {0.f, 0.f, 0.f, 0.f};
  f32x4 acc[3][4];
  #pragma unroll
  for (int conv = 0; conv < 3; ++conv)
    #pragma unroll
    for (int ht = 0; ht < 4; ++ht){
      bf16x8 bw = ldbf8(wfE + (size_t)((conv*64) + ht*16 + llo)*32 + lhi*8);
      acc[conv][ht] = __builtin_amdgcn_mfma_f32_16x16x32_bf16(af, bw, z, 0, 0, 0);
    }

  #pragma unroll
  for (int ht = 0; ht < 4; ++ht){
    const int h = ht*16 + llo;
    #pragma unroll
    for (int i = 0; i < 4; ++i){
      float p = acc[0][ht][i];
      float q = acc[1][ht][i];
      float r = acc[2][ht][i];
      float sig = 1.f / (1.f + __expf(-q));
      float o = fmaxf(fmaf(p, sig, r), 0.f);
      const int n = nb*64 + wv*16 + lhi*4 + i;
      U[((size_t)n * MM + bt) * 64 + h] = f2bf(o);   // [n][m][c]
    }
  }
}

// ---------------- FUSED spmv1 + cheb GEMM (L2-correct tiling, plain gathers) ----------------
// block <-> (mg of 4 m-planes, ng of 16 nodes); 64-row tile = 16n x 4m.
// Phase A: wave w serves nodes ng*16+w*4+[0,4): per edge ONE 512B gather
// (4 m-planes) -- per-XCD working set = 4096 x 512B = 2MB, L2-resident.
// Results -> XOR-swizzled LDS. Phase B: cheb MFMA. V never touches global.
// Plain loads (nt: 3.6x HBM fetch R8; sc0: null R11; barrier-free: write
// amplification R12 -- this barrier'd v2 form is the measured optimum).

__global__ __launch_bounds__(256) void k_fused_sc(
    const unsigned short* __restrict__ U,
    const int* __restrict__ rowptr, const ui2* __restrict__ csre,
    const unsigned short* __restrict__ wfD, const float* __restrict__ cheb_b,
    unsigned short* __restrict__ G0bf, unsigned short* __restrict__ P){
  __shared__ unsigned short vlds[4096];   // 64 rows x 64 ch bf16, XOR-swizzled
  const int tid = threadIdx.x;
  int blk = blockIdx.x;
  blk = (blk & 7) * 1536 + (blk >> 3);    // XCD chunk swizzle (12288/8 = 1536)
  const int mg = blk >> 8;                // [0,48): 4 m-planes
  const int ng = blk & 255;               // [0,256): 16 nodes
  const int wv = tid >> 6, lane = tid & 63;
  const int p = lane >> 4, c4 = lane & 15;           // plane, 4-ch block
  const int loff = p*64 + c4*4;                      // elem offset in 512B slab

  const unsigned short* Umg = U + (size_t)mg * 256;  // + src*12288 + loff

  // ---- Phase A: V rows accumulate (4 nodes per wave) ----
  #pragma unroll
  for (int j = 0; j < 4; ++j){
    const int n = ng*16 + wv*4 + j;
    const int e0 = __builtin_amdgcn_readfirstlane(rowptr[n]);
    const int e1 = __builtin_amdgcn_readfirstlane(rowptr[n+1]);
    float a0 = 0.f, a1 = 0.f, a2 = 0.f, a3 = 0.f;
    for (int e = e0; e < e1; e += 8){
      int ss[8]; float ww[8];
      #pragma unroll
      for (int u = 0; u < 8; ++u){
        const int ee = e + u;
        const bool in = ee < e1;
        const ui2 mw = csre[in ? ee : e0];
        ss[u] = (int)__builtin_amdgcn_readfirstlane(mw.x);
        const float wvv = __builtin_bit_cast(float, __builtin_amdgcn_readfirstlane(mw.y));
        ww[u] = in ? wvv : 0.f;
      }
      ui2 d[8];
      #pragma unroll
      for (int u = 0; u < 8; ++u)
        d[u] = *reinterpret_cast<const ui2*>(Umg + (size_t)ss[u] * 12288 + loff);
      #pragma unroll
      for (int u = 0; u < 8; ++u){
        const float w = ww[u];
        a0 = fmaf(w, lo2f(d[u].x), a0);
        a1 = fmaf(w, hi2f(d[u].x), a1);
        a2 = fmaf(w, lo2f(d[u].y), a2);
        a3 = fmaf(w, hi2f(d[u].y), a3);
      }
    }
    const int r = (wv*4 + j)*4 + p;       // tile row = local_n*4 + local_m
    const int byteoff = r*128 + ((c4*8) ^ ((r & 7) << 4));
    ushort4 pk;
    pk.x = f2bf(a0); pk.y = f2bf(a1); pk.z = f2bf(a2); pk.w = f2bf(a3);
    *reinterpret_cast<ushort4*>(reinterpret_cast<char*>(vlds) + byteoff) = pk;
  }
  __syncthreads();

  // ---- Phase B: cheb MFMA ----
  const int lhi = lane >> 4, llo = lane & 15;
  const int c = wv * 16 + llo;

  bf16x8 bA[2], bW1[2], bW2[2];
  #pragma unroll
  for (int kt = 0; kt < 2; ++kt){
    bA[kt]  = ldbf8(wfD + (size_t)((0*2 + kt)*64 + c)*32 + lhi*8);
    bW1[kt] = ldbf8(wfD + (size_t)((1*2 + kt)*64 + c)*32 + lhi*8);
    bW2[kt] = ldbf8(wfD + (size_t)((2*2 + kt)*64 + c)*32 + lhi*8);
  }
  const f32x4 z = {0.f, 0.f, 0.f, 0.f};
  f32x4 accG[4], accP[4];
  #pragma unroll
  for (int rt = 0; rt < 4; ++rt){ accG[rt] = z; accP[rt] = z; }

  #pragma unroll
  for (int rt = 0; rt < 4; ++rt){
    const int m = rt*16 + llo;            // tile row
    const size_t gr = ((size_t)(ng*16 + (m >> 2))) * MM + mg*4 + (m & 3);
    const unsigned short* up = U + gr*64 + lhi*8;
    #pragma unroll
    for (int kt = 0; kt < 2; ++kt){
      bf16x8 au = ldbf8(up + kt*32);
      const int vboff = m*128 + (((kt*64) + lhi*16) ^ ((m & 7) << 4));
      bf16x8 av = __builtin_bit_cast(bf16x8, *reinterpret_cast<const us8*>(
          reinterpret_cast<const char*>(vlds) + vboff));
      accG[rt] = __builtin_amdgcn_mfma_f32_16x16x32_bf16(au, bA[kt],  accG[rt], 0, 0, 0);
      accG[rt] = __builtin_amdgcn_mfma_f32_16x16x32_bf16(av, bW1[kt], accG[rt], 0, 0, 0);
      accP[rt] = __builtin_amdgcn_mfma_f32_16x16x32_bf16(av, bW2[kt], accP[rt], 0, 0, 0);
    }
  }
  const float bias = cheb_b[c];
  #pragma unroll
  for (int rt = 0; rt < 4; ++rt){
    #pragma unroll
    for (int i = 0; i < 4; ++i){
      const int mrow = rt*16 + lhi*4 + i;  // tile row of this D element
      const size_t gr = ((size_t)(ng*16 + (mrow >> 2))) * MM + mg*4 + (mrow & 3);
      G0bf[gr*64 + c] = f2bf(accG[rt][i] + bias);
      P[gr*64 + c]    = f2bf(accP[rt][i]);
    }
  }
}

// ---------------- spmv2 on [n][m][c]: g = relu(G0 + S·P), plain gathers ----------------

__global__ __launch_bounds__(256) void k_spmv2(
    const unsigned short* __restrict__ X,
    const int* __restrict__ rowptr,
    const ui2* __restrict__ csre,
    const unsigned short* __restrict__ G0bf,
    unsigned short* __restrict__ Y){
  constexpr int EU = 16;
  const int nb = gridDim.x;
  int bs = (blockIdx.x & 7) * (nb >> 3) + (blockIdx.x >> 3);
  int wg = bs * 4 + (threadIdx.x >> 6);
  wg = __builtin_amdgcn_readfirstlane(wg);
  const int lane = threadIdx.x & 63;
  const int mg = wg >> 12, n = wg & (NN-1);
  const int e0 = __builtin_amdgcn_readfirstlane(rowptr[n]);
  const int e1 = __builtin_amdgcn_readfirstlane(rowptr[n+1]);
  const unsigned short* Xmg = X + (size_t)mg * 256;
  const int loff = lane * 4;

  float a0 = 0.f, a1 = 0.f, a2 = 0.f, a3 = 0.f;

  for (int e = e0; e < e1; e += EU){
    int ss[EU]; float ww[EU];
    #pragma unroll
    for (int u = 0; u < EU; ++u){
      const int ee = e + u;
      const bool in = ee < e1;
      const ui2 mw = csre[in ? ee : e0];
      ss[u] = (int)__builtin_amdgcn_readfirstlane(mw.x);
      const float wv = __builtin_bit_cast(float, __builtin_amdgcn_readfirstlane(mw.y));
      ww[u] = in ? wv : 0.f;
    }
    ui2 d[EU];
    #pragma unroll
    for (int u = 0; u < EU; ++u)
      d[u] = *reinterpret_cast<const ui2*>(Xmg + (size_t)ss[u] * 12288 + loff);
    #pragma unroll
    for (int u = 0; u < EU; ++u){
      const float w = ww[u];
      a0 = fmaf(w, lo2f(d[u].x), a0);
      a1 = fmaf(w, hi2f(d[u].x), a1);
      a2 = fmaf(w, lo2f(d[u].y), a2);
      a3 = fmaf(w, hi2f(d[u].y), a3);
    }
  }

  const size_t oidx = (size_t)n * 12288 + mg * 256 + loff;
  {
    ui2 gd = *reinterpret_cast<const ui2*>(G0bf + oidx);
    a0 = fmaxf(a0 + lo2f(gd.x), 0.f);
    a1 = fmaxf(a1 + hi2f(gd.x), 0.f);
    a2 = fmaxf(a2 + lo2f(gd.y), 0.f);
    a3 = fmaxf(a3 + hi2f(gd.y), 0.f);
  }
  ui2 o;
  o.x = (unsigned)f2bf(a0) | ((unsigned)f2bf(a1) << 16);
  o.y = (unsigned)f2bf(a2) | ((unsigned)f2bf(a3) << 16);
  *reinterpret_cast<ui2*>(Y + oidx) = o;
}

// ---------------- temporal conv 2: persistent blocks, reg weights, LDS-staged g ----------------

__device__ __forceinline__ void t2_load(const unsigned short* __restrict__ g,
                                        int tile, int tid, uint4* st){
  const int bt = tile >> 6, nb = tile & 63;
  const int t = bt - (bt / TT) * TT;
  #pragma unroll
  for (int j = 0; j < 6; ++j){
    const int plane = j >> 1;
    const int tp = t + plane - 1;
    const int idx = ((j & 1) << 8) + tid;      // 0..511 within plane
    const int row = idx >> 3;                  // 0..63
    const int innerb = (idx & 7) * 16;         // byte offset within 128B row
    if (tp >= 0 && tp < TT){
      const unsigned short* sp = g
          + ((size_t)(nb*64 + row) * MM + (bt + plane - 1)) * 64
          + ((innerb ^ ((row & 7) << 4)) >> 1);
      st[j] = *reinterpret_cast<const uint4*>(sp);
    } else {
      st[j] = make_uint4(0u, 0u, 0u, 0u);
    }
  }
}

__global__ __launch_bounds__(256, 2) void k_temporal2(
    const unsigned short* __restrict__ g,
    const unsigned short* __restrict__ wfF,
    const float* __restrict__ b1, const float* __restrict__ b2, const float* __restrict__ b3,
    unsigned short* __restrict__ obf, float* __restrict__ bnstat2){
  __shared__ unsigned short smem[2][12288];    // 2 x 24KB
  const int tid = threadIdx.x;
  const int wv = tid >> 6, lane = tid & 63;
  const int lhi = lane >> 4, llo = lane & 15;
  const int h = wv * 16 + llo;                 // A-fragment row
  const int h0 = wv * 16 + lhi * 4;            // D rows: 4 consecutive h per thread

  bf16x8 bw[3][6];
  #pragma unroll
  for (int cv = 0; cv < 3; ++cv)
    #pragma unroll
    for (int kt = 0; kt < 6; ++kt)
      bw[cv][kt] = ldbf8(wfF + (size_t)((cv*6 + kt)*64 + h)*32 + lhi*8);

  const f32x4 vb1 = *reinterpret_cast<const f32x4*>(b1 + h0);
  const f32x4 vb2 = *reinterpret_cast<const f32x4*>(b2 + h0);
  const f32x4 vb3 = *reinterpret_cast<const f32x4*>(b3 + h0);
  const f32x4 z = {0.f, 0.f, 0.f, 0.f};

  uint4 st[6];
  t2_load(g, blockIdx.x, tid, st);
  #pragma unroll
  for (int j = 0; j < 6; ++j)
    *reinterpret_cast<uint4*>(&smem[0][(size_t)(j*256 + tid) * 8]) = st[j];
  __syncthreads();

  int cur = 0;
  for (int it = 0; it < T2_NT; ++it){
    const int tile = blockIdx.x + it * T2_GRID;
    const int bt = tile >> 6, nb = tile & 63;

    if (it + 1 < T2_NT)
      t2_load(g, tile + T2_GRID, tid, st);     // issue early; consumed after compute

    const unsigned short* sb = smem[cur];
    f32x4 acc[3][4];
    #pragma unroll
    for (int cv = 0; cv < 3; ++cv)
      #pragma unroll
      for (int rt = 0; rt < 4; ++rt) acc[cv][rt] = z;

    #pragma unroll
    for (int kt = 0; kt < 6; ++kt){
      const int dt = kt >> 1;
      const int qb = (kt & 1) * 64 + lhi * 16; // byte offset within row
      #pragma unroll
      for (int rt = 0; rt < 4; ++rt){
        const int row = rt*16 + llo;
        bf16x8 a = __builtin_bit_cast(bf16x8, *reinterpret_cast<const us8*>(
            sb + dt*4096 + row*64 + ((qb ^ ((row & 7) << 4)) >> 1)));
        acc[0][rt] = __builtin_amdgcn_mfma_f32_16x16x32_bf16(bw[0][kt], a, acc[0][rt], 0, 0, 0);
        acc[1][rt] = __builtin_amdgcn_mfma_f32_16x16x32_bf16(bw[1][kt], a, acc[1][rt], 0, 0, 0);
        acc[2][rt] = __builtin_amdgcn_mfma_f32_16x16x32_bf16(bw[2][kt], a, acc[2][rt], 0, 0, 0);
      }
    }

    f32x4 lsum = z, lsq = z;
    #pragma unroll
    for (int rt = 0; rt < 4; ++rt){
      const int n = nb*64 + rt*16 + llo;       // D col
      ushort4 pk;
      unsigned short* pp = reinterpret_cast<unsigned short*>(&pk);
      #pragma unroll
      for (int i = 0; i < 4; ++i){
        float p = acc[0][rt][i] + vb1[i];
        float q = acc[1][rt][i] + vb2[i];
        float r = acc[2][rt][i] + vb3[i];
        float sig = 1.f / (1.f + __expf(-q));
        float o = fmaxf(fmaf(p, sig, r), 0.f);
        pp[i] = f2bf(o);
        lsum[i] += o; lsq[i] = fmaf(o, o, lsq[i]);
      }
      *reinterpret_cast<ushort4*>(&obf[((size_t)bt * NN + n) * 64 + h0]) = pk;
    }
    #pragma unroll
    for (int m = 1; m < 16; m <<= 1){
      #pragma unroll
      for (int i = 0; i < 4; ++i){
        lsum[i] += __shfl_xor(lsum[i], m);
        lsq[i]  += __shfl_xor(lsq[i], m);
      }
    }
    if (llo == 0){
      float* bs = bnstat2 + (size_t)(tile & (NBUCKET-1)) * 128;
      #pragma unroll
      for (int i = 0; i < 4; ++i){
        atomicAdd(&bs[h0 + i], lsum[i]);
        atomicAdd(&bs[64 + h0 + i], lsq[i]);
      }
    }

    if (it + 1 < T2_NT){
      #pragma unroll
      for (int j = 0; j < 6; ++j)
        *reinterpret_cast<uint4*>(&smem[cur ^ 1][(size_t)(j*256 + tid) * 8]) = st[j];
      __syncthreads();
      cur ^= 1;
    }
  }
}

// ---------------- BN bucket reduce + apply ----------------

__global__ void k_bnfinal(const float* __restrict__ bnstat2, float* __restrict__ bnstat){
  int t = threadIdx.x;   // 0..127
  float s = 0.f;
  for (int b = 0; b < NBUCKET; ++b) s += bnstat2[(size_t)b * 128 + t];
  bnstat[t] = s;
}

__global__ __launch_bounds__(256) void k_bnapply(
    const unsigned short* __restrict__ obf, float* __restrict__ out,
    const float* __restrict__ bnstat,
    const float* __restrict__ gamma, const float* __restrict__ beta){
  __shared__ float ssc[64], sfb[64];
  int tid = threadIdx.x;
  if (tid < 64){
    const float inv = 1.f / (float)ROWS;
    float s = bnstat[tid], q = bnstat[64 + tid];
    float mu = s * inv;
    float var = q * inv - mu * mu;
    if (var < 0.f) var = 0.f;
    float sc = gamma[tid] * rsqrtf(var + 1e-5f);
    ssc[tid] = sc;
    sfb[tid] = beta[tid] - mu * sc;   // out = f*sc + sfb
  }
  __syncthreads();
  const int ngrp = TOT / 8;
  for (int i = blockIdx.x * 256 + tid; i < ngrp; i += gridDim.x * 256){
    us8 v = *reinterpret_cast<const us8*>(obf + (size_t)i * 8);
    const int c0 = (i * 8) & 63;
    f32x4 lo, hi;
    #pragma unroll
    for (int j = 0; j < 4; ++j)
      lo[j] = fmaf(bf2f(v[j]), ssc[c0 + j], sfb[c0 + j]);
    #pragma unroll
    for (int j = 0; j < 4; ++j)
      hi[j] = fmaf(bf2f(v[4 + j]), ssc[c0 + 4 + j], sfb[c0 + 4 + j]);
    *reinterpret_cast<f32x4*>(out + (size_t)i * 8)     = lo;
    *reinterpret_cast<f32x4*>(out + (size_t)i * 8 + 4) = hi;
  }
}

// ---------------- launch ----------------

extern "C" void kernel_launch(void* const* d_in, const int* in_sizes, int n_in,
                              void* d_out, int out_size, void* d_ws, size_t ws_size,
                              hipStream_t stream){
  const float* x     = (const float*)d_in[0];
  const int*   ei    = (const int*)d_in[1];
  const float* attr  = (const float*)d_in[2];
  const float* t1w1  = (const float*)d_in[3];
  const float* t1b1  = (const float*)d_in[4];
  const float* t1w2  = (const float*)d_in[5];
  const float* t1b2  = (const float*)d_in[6];
  const float* t1w3  = (const float*)d_in[7];
  const float* t1b3  = (const float*)d_in[8];
  const float* chebW = (const float*)d_in[9];
  const float* chebB = (const float*)d_in[10];
  const float* t2w1  = (const float*)d_in[11];
  const float* t2b1  = (const float*)d_in[12];
  const float* t2w2  = (const float*)d_in[13];
  const float* t2b2  = (const float*)d_in[14];
  const float* t2w3  = (const float*)d_in[15];
  const float* t2b3  = (const float*)d_in[16];
  const float* bng   = (const float*)d_in[17];
  const float* bnb   = (const float*)d_in[18];
  const int* src = ei;
  const int* dst = ei + EE;

  const size_t SZ_U = (size_t)ROWS * 64 * 2;
  char* ws = (char*)d_ws;
  unsigned short* bufA = (unsigned short*)ws;
  unsigned short* bufB = (unsigned short*)(ws + SZ_U);
  size_t off = 2 * SZ_U;
  float* deg    = (float*)(ws + off); off += 4096 * 4;
  int*   cnt    = (int*)(ws + off);   off += 4096 * 4;
  int*   rowptr = (int*)(ws + off);   off += 4128 * 4;
  int*   fill   = (int*)(ws + off);   off += 4096 * 4;
  float* wn     = (float*)(ws + off); off += EE * 4;
  ui2*   csre   = (ui2*)(ws + off);   off += EE * 8;
  unsigned short* wfD = (unsigned short*)(ws + off); off += 12288 * 2;
  unsigned short* wfF = (unsigned short*)(ws + off); off += 36864 * 2;
  unsigned short* wfE = (unsigned short*)(ws + off); off += 6144 * 2;
  float* bnstat = (float*)(ws + off); off += 128 * 4;
  float* bnstat2 = (float*)(ws + off); off += NBUCKET * 128 * 4;

  unsigned short* G0bf = (unsigned short*)d_out;  // bf16 cheb pre-relu ([n][m][c] rows)

  hipMemsetAsync(deg, 0, 4096 * 4, stream);
  hipMemsetAsync(cnt, 0, 4096 * 4, stream);
  hipMemsetAsync(bnstat2, 0, NBUCKET * 128 * 4, stream);

  k_deg_cnt<<<EE/256, 256, 0, stream>>>(src, dst, attr, deg, cnt);
  k_wn<<<EE/256, 256, 0, stream>>>(src, dst, attr, deg, wn);
  k_scan<<<1, 1024, 0, stream>>>(cnt, rowptr, fill);
  k_csr<<<EE/256, 256, 0, stream>>>(dst, src, wn, fill, csre);
  k_wprep<<<64, 256, 0, stream>>>(chebW, t2w1, t2w2, t2w3,
                                  t1w1, t1b1, t1w2, t1b2, t1w3, t1b3,
                                  wfD, wfF, wfE);

  k_temporal1<<<ROWS/64, 256, 0, stream>>>(x, wfE, bufA /* U */);
  k_fused_sc<<<ROWS/64, 256, 0, stream>>>(bufA /* U */, rowptr, csre, wfD, chebB,
                                          G0bf, bufB /* P */);
  k_spmv2<<<(MM/4)*NN/4, 256, 0, stream>>>(bufB /* P */, rowptr, csre, G0bf, bufA /* g */);
  k_temporal2<<<T2_GRID, 256, 0, stream>>>(bufA /* g */, wfF, t2b1, t2b2, t2b3,
                                           bufB /* obf */, bnstat2);
  k_bnfinal<<<1, 128, 0, stream>>>(bnstat2, bnstat);
  k_bnapply<<<2048, 256, 0, stream>>>(bufB /* obf */, (float*)d_out, bnstat, bng, bnb);
}